// Round 1
// baseline (77.057 us; speedup 1.0000x reference)
//
#include <hip/hip_runtime.h>
#include <hip/hip_bf16.h>

typedef unsigned short ushort_t;
typedef __attribute__((ext_vector_type(8))) short short8;
typedef __attribute__((ext_vector_type(4))) float f32x4;

__device__ __forceinline__ ushort_t f2b(float x) {
    unsigned int u = __builtin_bit_cast(unsigned int, x);
    u += 0x7FFFu + ((u >> 16) & 1u);   // round-to-nearest-even
    return (ushort_t)(u >> 16);
}

// ---- prepass: fp32 -> bf16 table conversion (vectorized: 4 floats/thread) ----
__global__ __launch_bounds__(256) void conv_bf16(const float* __restrict__ src,
                                                 ushort_t* __restrict__ dst, int n4) {
    int t = blockIdx.x * blockDim.x + threadIdx.x;
    if (t < n4) {
        float4 f = reinterpret_cast<const float4*>(src)[t];
        ushort4 o;
        o.x = f2b(f.x); o.y = f2b(f.y); o.z = f2b(f.z); o.w = f2b(f.w);
        reinterpret_cast<ushort4*>(dst)[t] = o;
    }
}

// ---- prepass: W1 [32][128] fp32 -> W1T [128][32] bf16 ----
__global__ __launch_bounds__(256) void conv_w1t(const float* __restrict__ W1,
                                                ushort_t* __restrict__ w1t) {
    int t = blockIdx.x * blockDim.x + threadIdx.x;
    if (t < 128 * 32) {
        int k = t >> 5, j = t & 31;
        w1t[t] = f2b(W1[j * 128 + k]);
    }
}

// ---- main: 16 edges per wave-iteration via mfma_f32_16x16x32_bf16 ----
__global__ __launch_bounds__(256) void edge_mlp_mfma(
    const ushort_t* __restrict__ ubf, const ushort_t* __restrict__ ibf,
    const ushort_t* __restrict__ w1t, const float* __restrict__ b1,
    const float* __restrict__ w2, const float* __restrict__ b2v,
    const int* __restrict__ idx, float* __restrict__ out,
    long E, long ntiles)
{
    const int l  = threadIdx.x & 63;
    const int lj = l & 15;   // A-row / D-col / B-col within tile
    const int lg = l >> 4;   // k-group (8 k's each); D rows lg*4..lg*4+3

    long wglobal = (long)blockIdx.x * (blockDim.x >> 6) + (threadIdx.x >> 6);
    long nwaves  = (long)gridDim.x * (blockDim.x >> 6);

    // B fragments: W1T[k][j], lane holds k = kt*32 + lg*8 + e, j = c*16 + lj
    short8 bfrag[4][2];
#pragma unroll
    for (int kt = 0; kt < 4; ++kt)
#pragma unroll
        for (int c = 0; c < 2; ++c) {
            short8 v;
#pragma unroll
            for (int e = 0; e < 8; ++e)
                v[e] = (short)w1t[(kt * 32 + lg * 8 + e) * 32 + c * 16 + lj];
            bfrag[kt][c] = v;
        }

    const float bj0 = b1[lj],      bj1 = b1[16 + lj];
    const float w2j0 = w2[lj],     w2j1 = w2[16 + lj];
    const float bb2 = b2v[0];

    for (long tile = wglobal; tile < ntiles; tile += nwaves) {
        long e0 = tile * 16;
        long er = e0 + lj;
        if (er >= E) er = E - 1;                 // tail guard (no-op here: E%16==0)
        int u  = idx[er];
        int it = idx[E + er];
        const ushort_t* urow = ubf + (long)u  * 64;
        const ushort_t* irow = ibf + (long)it * 64;

        short8 a0 = *reinterpret_cast<const short8*>(urow + lg * 8);
        short8 a1 = *reinterpret_cast<const short8*>(urow + 32 + lg * 8);
        short8 a2 = *reinterpret_cast<const short8*>(irow + lg * 8);
        short8 a3 = *reinterpret_cast<const short8*>(irow + 32 + lg * 8);

        f32x4 acc0 = {0.f, 0.f, 0.f, 0.f};
        f32x4 acc1 = {0.f, 0.f, 0.f, 0.f};
        acc0 = __builtin_amdgcn_mfma_f32_16x16x32_bf16(a0, bfrag[0][0], acc0, 0, 0, 0);
        acc1 = __builtin_amdgcn_mfma_f32_16x16x32_bf16(a0, bfrag[0][1], acc1, 0, 0, 0);
        acc0 = __builtin_amdgcn_mfma_f32_16x16x32_bf16(a1, bfrag[1][0], acc0, 0, 0, 0);
        acc1 = __builtin_amdgcn_mfma_f32_16x16x32_bf16(a1, bfrag[1][1], acc1, 0, 0, 0);
        acc0 = __builtin_amdgcn_mfma_f32_16x16x32_bf16(a2, bfrag[2][0], acc0, 0, 0, 0);
        acc1 = __builtin_amdgcn_mfma_f32_16x16x32_bf16(a2, bfrag[2][1], acc1, 0, 0, 0);
        acc0 = __builtin_amdgcn_mfma_f32_16x16x32_bf16(a3, bfrag[3][0], acc0, 0, 0, 0);
        acc1 = __builtin_amdgcn_mfma_f32_16x16x32_bf16(a3, bfrag[3][1], acc1, 0, 0, 0);

        // epilogue: bias + leaky + W2 dot (fp32), 16-lane reduce
        float s0, s1, s2, s3;
#pragma unroll
        for (int r = 0; r < 4; ++r) {
            float h0 = acc0[r] + bj0; h0 = h0 >= 0.f ? h0 : 0.2f * h0;
            float h1 = acc1[r] + bj1; h1 = h1 >= 0.f ? h1 : 0.2f * h1;
            float p = h0 * w2j0 + h1 * w2j1;
            p += __shfl_xor(p, 1);
            p += __shfl_xor(p, 2);
            p += __shfl_xor(p, 4);
            p += __shfl_xor(p, 8);
            if (r == 0) s0 = p; else if (r == 1) s1 = p; else if (r == 2) s2 = p; else s3 = p;
        }
        if (lj < 4) {
            float p = (lj == 0) ? s0 : (lj == 1) ? s1 : (lj == 2) ? s2 : s3;
            long eo = e0 + lg * 4 + lj;           // D row = lg*4 + r, r = lj
            if (eo < E) {
                float lgt = p + bb2;
                out[eo] = 1.0f / (1.0f + expf(-lgt));
            }
        }
    }
}

// ---- fallback (ws too small): fp32 VALU, thread-per-edge, W1T in LDS ----
__global__ __launch_bounds__(256) void edge_mlp_fp32(
    const float* __restrict__ ue, const float* __restrict__ ie,
    const float* __restrict__ W1, const float* __restrict__ b1,
    const float* __restrict__ w2, const float* __restrict__ b2v,
    const int* __restrict__ idx, float* __restrict__ out, long E)
{
    __shared__ float w1s[128][32];   // [k][j]
    for (int t = threadIdx.x; t < 4096; t += blockDim.x) {
        int k = t >> 5, j = t & 31;
        w1s[k][j] = W1[j * 128 + k];
    }
    __syncthreads();
    long e = (long)blockIdx.x * blockDim.x + threadIdx.x;
    if (e >= E) return;
    int u = idx[e], it = idx[E + e];
    const float* ur = ue + (long)u * 64;
    const float* ir = ie + (long)it * 64;
    float acc[32];
#pragma unroll
    for (int j = 0; j < 32; ++j) acc[j] = b1[j];
    for (int k = 0; k < 64; k += 4) {
        float4 f = *reinterpret_cast<const float4*>(ur + k);
        float fv[4] = {f.x, f.y, f.z, f.w};
#pragma unroll
        for (int q = 0; q < 4; ++q)
#pragma unroll
            for (int j = 0; j < 32; ++j) acc[j] += w1s[k + q][j] * fv[q];
    }
    for (int k = 0; k < 64; k += 4) {
        float4 f = *reinterpret_cast<const float4*>(ir + k);
        float fv[4] = {f.x, f.y, f.z, f.w};
#pragma unroll
        for (int q = 0; q < 4; ++q)
#pragma unroll
            for (int j = 0; j < 32; ++j) acc[j] += w1s[64 + k + q][j] * fv[q];
    }
    float lgt = b2v[0];
#pragma unroll
    for (int j = 0; j < 32; ++j) {
        float h = acc[j]; h = h >= 0.f ? h : 0.2f * h;
        lgt += h * w2[j];
    }
    out[e] = 1.0f / (1.0f + expf(-lgt));
}

extern "C" void kernel_launch(void* const* d_in, const int* in_sizes, int n_in,
                              void* d_out, int out_size, void* d_ws, size_t ws_size,
                              hipStream_t stream) {
    const float* ue  = (const float*)d_in[0];
    const float* ie  = (const float*)d_in[1];
    const float* W1  = (const float*)d_in[2];
    const float* b1  = (const float*)d_in[3];
    const float* w2  = (const float*)d_in[4];
    const float* b2v = (const float*)d_in[5];
    const int*   idx = (const int*)d_in[6];   // harness delivers integer inputs as int32
    float* out = (float*)d_out;

    long nu = in_sizes[0] / 64;
    long ni = in_sizes[1] / 64;
    long E  = in_sizes[6] / 2;

    size_t need = (size_t)(nu + ni) * 64 * 2 + 128 * 32 * 2;
    if (ws_size >= need) {
        ushort_t* ubf = (ushort_t*)d_ws;
        ushort_t* ibf = ubf + (size_t)nu * 64;
        ushort_t* w1t = ibf + (size_t)ni * 64;
        int n4u = (int)(nu * 16), n4i = (int)(ni * 16);
        conv_bf16<<<(n4u + 255) / 256, 256, 0, stream>>>(ue, ubf, n4u);
        conv_bf16<<<(n4i + 255) / 256, 256, 0, stream>>>(ie, ibf, n4i);
        conv_w1t<<<16, 256, 0, stream>>>(W1, w1t);
        long ntiles = (E + 15) / 16;
        int blocks = 2048;
        edge_mlp_mfma<<<blocks, 256, 0, stream>>>(ubf, ibf, w1t, b1, w2, b2v,
                                                  idx, out, E, ntiles);
    } else {
        edge_mlp_fp32<<<(int)((E + 255) / 256), 256, 0, stream>>>(
            ue, ie, W1, b1, w2, b2v, idx, out, E);
    }
}

// Round 2
// 68.062 us; speedup vs baseline: 1.1322x; 1.1322x over previous
//
#include <hip/hip_runtime.h>

typedef unsigned short ushort_t;
typedef __attribute__((ext_vector_type(8))) short short8;
typedef __attribute__((ext_vector_type(4))) float f32x4;

__device__ __forceinline__ ushort_t f2b(float x) {
    unsigned int u = __builtin_bit_cast(unsigned int, x);
    u += 0x7FFFu + ((u >> 16) & 1u);   // round-to-nearest-even
    return (ushort_t)(u >> 16);
}

// ---- fused prepass: ue, ie, W1 -> bf16 (4 floats per thread) ----
__global__ __launch_bounds__(256) void conv_fused(
    const float* __restrict__ ue, const float* __restrict__ ie,
    const float* __restrict__ W1,
    ushort_t* __restrict__ ubf, ushort_t* __restrict__ ibf,
    ushort_t* __restrict__ w1bf, int n4u, int n4i)
{
    int t = blockIdx.x * blockDim.x + threadIdx.x;
    const float* s; ushort_t* d; int off;
    if (t < n4u)              { s = ue; d = ubf;  off = t; }
    else if (t < n4u + n4i)   { s = ie; d = ibf;  off = t - n4u; }
    else if (t < n4u + n4i + 1024) { s = W1; d = w1bf; off = t - n4u - n4i; }
    else return;
    float4 f = reinterpret_cast<const float4*>(s)[off];
    ushort4 o;
    o.x = f2b(f.x); o.y = f2b(f.y); o.z = f2b(f.z); o.w = f2b(f.w);
    reinterpret_cast<ushort4*>(d)[off] = o;
}

// ---- main: 64 edges per wave-iteration; A = W1 (bf16), B = gathered edges ----
__global__ __launch_bounds__(256) void edge_mlp(
    const ushort_t* __restrict__ ubf, const ushort_t* __restrict__ ibf,
    const ushort_t* __restrict__ w1bf, const float* __restrict__ b1,
    const float* __restrict__ w2, const float* __restrict__ b2v,
    const int* __restrict__ idx, float* __restrict__ out,
    long E, long ngroups)
{
    const int l  = threadIdx.x & 63;
    const int lj = l & 15;   // A-row (j) / D-col (edge) within tile
    const int lg = l >> 4;   // k-group; D rows lg*4..lg*4+3

    long wid = (long)blockIdx.x * (blockDim.x >> 6) + (threadIdx.x >> 6);
    long nw  = (long)gridDim.x * (blockDim.x >> 6);

    // A fragments: W1[j][k], j = g*16+lj, k = kt*32 + lg*8 + e (16B contiguous)
    short8 afrag[4][2];
#pragma unroll
    for (int kt = 0; kt < 4; ++kt)
#pragma unroll
        for (int g = 0; g < 2; ++g)
            afrag[kt][g] = *reinterpret_cast<const short8*>(
                w1bf + (g * 16 + lj) * 128 + kt * 32 + lg * 8);

    // bias folded into MFMA C-init; w2 per-lane slice
    f32x4 binit[2]; float w2v[2][4];
#pragma unroll
    for (int g = 0; g < 2; ++g)
#pragma unroll
        for (int r = 0; r < 4; ++r) {
            binit[g][r] = b1[g * 16 + lg * 4 + r];
            w2v[g][r]   = w2[g * 16 + lg * 4 + r];
        }
    const float bb2 = b2v[0];

    long g0 = wid;
    if (g0 >= ngroups) return;
    {
        long el = g0 * 64 + l; if (el >= E) el = E - 1;
        // coalesced idx prefetch: lane l <-> edge l of the group
        long dummy = el;
        (void)dummy;
    }
    long el0 = g0 * 64 + l; if (el0 >= E) el0 = E - 1;
    int uidx = idx[el0];
    int iidx = idx[E + el0];

    for (long grp = g0; grp < ngroups; ) {
        long base = grp * 64;

        // distribute row indices, issue all 16 scattered row loads
        short8 b[4][4];
#pragma unroll
        for (int t = 0; t < 4; ++t) {
            int ut = __shfl(uidx, t * 16 + lj);
            int it = __shfl(iidx, t * 16 + lj);
            const ushort_t* ur = ubf + (long)ut * 64;
            const ushort_t* ir = ibf + (long)it * 64;
            b[t][0] = *reinterpret_cast<const short8*>(ur + lg * 8);
            b[t][1] = *reinterpret_cast<const short8*>(ur + 32 + lg * 8);
            b[t][2] = *reinterpret_cast<const short8*>(ir + lg * 8);
            b[t][3] = *reinterpret_cast<const short8*>(ir + 32 + lg * 8);
        }

        // prefetch next group's indices (coalesced)
        long gn = grp + nw;
        if (gn < ngroups) {
            long en = gn * 64 + l; if (en >= E) en = E - 1;
            uidx = idx[en];
            iidx = idx[E + en];
        }

        float pt[4];
#pragma unroll
        for (int t = 0; t < 4; ++t) {
            f32x4 acc0 = binit[0], acc1 = binit[1];
#pragma unroll
            for (int kt = 0; kt < 4; ++kt) {
                acc0 = __builtin_amdgcn_mfma_f32_16x16x32_bf16(afrag[kt][0], b[t][kt], acc0, 0, 0, 0);
                acc1 = __builtin_amdgcn_mfma_f32_16x16x32_bf16(afrag[kt][1], b[t][kt], acc1, 0, 0, 0);
            }
            // leaky + W2 partial dot (8 of 32 h's per lane), then reduce over lg groups
            float p = 0.f;
#pragma unroll
            for (int r = 0; r < 4; ++r) {
                float y0 = acc0[r], y1 = acc1[r];
                float h0 = fmaxf(y0, 0.2f * y0);
                float h1 = fmaxf(y1, 0.2f * y1);
                p = fmaf(h0, w2v[0][r], p);
                p = fmaf(h1, w2v[1][r], p);
            }
            p += __shfl_xor(p, 16);
            p += __shfl_xor(p, 32);
            pt[t] = p;   // every lane now has tile-t logit for edge position lj
        }

        // lane l = lg*16+lj wants edge base+l = tile lg, position lj
        float pv = (lg == 0) ? pt[0] : (lg == 1) ? pt[1] : (lg == 2) ? pt[2] : pt[3];
        float x = pv + bb2;
        float z = __builtin_amdgcn_exp2f(-1.442695040888963f * x);
        float sig = __builtin_amdgcn_rcpf(1.f + z);
        long eo = base + l;
        if (eo < E) out[eo] = sig;   // one coalesced 256B store per group

        grp = gn;
    }
}

// ---- fallback (ws too small): fp32 VALU, thread-per-edge, W1 in LDS ----
__global__ __launch_bounds__(256) void edge_mlp_fp32(
    const float* __restrict__ ue, const float* __restrict__ ie,
    const float* __restrict__ W1, const float* __restrict__ b1,
    const float* __restrict__ w2, const float* __restrict__ b2v,
    const int* __restrict__ idx, float* __restrict__ out, long E)
{
    __shared__ float w1s[128][32];   // [k][j]
    for (int t = threadIdx.x; t < 4096; t += blockDim.x) {
        int k = t >> 5, j = t & 31;
        w1s[k][j] = W1[j * 128 + k];
    }
    __syncthreads();
    long e = (long)blockIdx.x * blockDim.x + threadIdx.x;
    if (e >= E) return;
    int u = idx[e], it = idx[E + e];
    const float* ur = ue + (long)u * 64;
    const float* ir = ie + (long)it * 64;
    float acc[32];
#pragma unroll
    for (int j = 0; j < 32; ++j) acc[j] = b1[j];
    for (int k = 0; k < 64; k += 4) {
        float4 f = *reinterpret_cast<const float4*>(ur + k);
        float fv[4] = {f.x, f.y, f.z, f.w};
#pragma unroll
        for (int q = 0; q < 4; ++q)
#pragma unroll
            for (int j = 0; j < 32; ++j) acc[j] += w1s[k + q][j] * fv[q];
    }
    for (int k = 0; k < 64; k += 4) {
        float4 f = *reinterpret_cast<const float4*>(ir + k);
        float fv[4] = {f.x, f.y, f.z, f.w};
#pragma unroll
        for (int q = 0; q < 4; ++q)
#pragma unroll
            for (int j = 0; j < 32; ++j) acc[j] += w1s[64 + k + q][j] * fv[q];
    }
    float lgt = b2v[0];
#pragma unroll
    for (int j = 0; j < 32; ++j) {
        float h = acc[j]; h = h >= 0.f ? h : 0.2f * h;
        lgt += h * w2[j];
    }
    out[e] = 1.0f / (1.0f + expf(-lgt));
}

extern "C" void kernel_launch(void* const* d_in, const int* in_sizes, int n_in,
                              void* d_out, int out_size, void* d_ws, size_t ws_size,
                              hipStream_t stream) {
    const float* ue  = (const float*)d_in[0];
    const float* ie  = (const float*)d_in[1];
    const float* W1  = (const float*)d_in[2];
    const float* b1  = (const float*)d_in[3];
    const float* w2  = (const float*)d_in[4];
    const float* b2v = (const float*)d_in[5];
    const int*   idx = (const int*)d_in[6];
    float* out = (float*)d_out;

    long nu = in_sizes[0] / 64;
    long ni = in_sizes[1] / 64;
    long E  = in_sizes[6] / 2;

    size_t need = (size_t)(nu + ni) * 64 * 2 + 4096 * 2;
    if (ws_size >= need) {
        ushort_t* ubf  = (ushort_t*)d_ws;
        ushort_t* ibf  = ubf + (size_t)nu * 64;
        ushort_t* w1bf = ibf + (size_t)ni * 64;
        int n4u = (int)(nu * 16), n4i = (int)(ni * 16);
        int total = n4u + n4i + 1024;
        conv_fused<<<(total + 255) / 256, 256, 0, stream>>>(ue, ie, W1, ubf, ibf, w1bf, n4u, n4i);
        long ngroups = (E + 63) / 64;
        int blocks = 2048;
        edge_mlp<<<blocks, 256, 0, stream>>>(ubf, ibf, w1bf, b1, w2, b2v,
                                             idx, out, E, ngroups);
    } else {
        edge_mlp_fp32<<<(int)((E + 255) / 256), 256, 0, stream>>>(
            ue, ie, W1, b1, w2, b2v, idx, out, E);
    }
}

// Round 3
// 45.562 us; speedup vs baseline: 1.6912x; 1.4938x over previous
//
#include <hip/hip_runtime.h>

typedef unsigned short ushort_t;
typedef __attribute__((ext_vector_type(8))) short short8;
typedef __attribute__((ext_vector_type(4))) float f32x4;
typedef __attribute__((ext_vector_type(2))) _Float16 h2v;
typedef __attribute__((ext_vector_type(4))) _Float16 h4v;

__device__ __forceinline__ ushort_t f2b(float x) {
    unsigned int u = __builtin_bit_cast(unsigned int, x);
    u += 0x7FFFu + ((u >> 16) & 1u);   // round-to-nearest-even
    return (ushort_t)(u >> 16);
}

__device__ __forceinline__ short8 pack8(const float* __restrict__ p) {
    float4 f0 = *reinterpret_cast<const float4*>(p);
    float4 f1 = *reinterpret_cast<const float4*>(p + 4);
    short8 v;
    v[0] = (short)f2b(f0.x); v[1] = (short)f2b(f0.y);
    v[2] = (short)f2b(f0.z); v[3] = (short)f2b(f0.w);
    v[4] = (short)f2b(f1.x); v[5] = (short)f2b(f1.y);
    v[6] = (short)f2b(f1.z); v[7] = (short)f2b(f1.w);
    return v;
}

// ---- precompute: hu[r][32] = W1[:, :64] @ ue[r] + b1 ; hi[r][32] = W1[:, 64:] @ ie[r]
// one wave per 16 table rows, MFMA 16x16x32_bf16, inline fp32->bf16 conversion
__global__ __launch_bounds__(256) void precompute_h(
    const float* __restrict__ ue, const float* __restrict__ ie,
    const float* __restrict__ W1, const float* __restrict__ b1,
    _Float16* __restrict__ hu, _Float16* __restrict__ hi,
    int nu, int ni, int ntu, int ntot)
{
    const int l  = threadIdx.x & 63;
    const int lj = l & 15;   // table row within tile (B col / D col)
    const int lg = l >> 4;   // k-group; D rows lg*4..lg*4+3

    int wid = blockIdx.x * (blockDim.x >> 6) + (threadIdx.x >> 6);
    if (wid >= ntot) return;
    const bool isU = wid < ntu;
    const float* tab = isU ? ue : ie;
    _Float16* ht = isU ? hu : hi;
    const int nrows = isU ? nu : ni;
    const int tb   = (isU ? wid : wid - ntu) * 16;
    const int toff = isU ? 0 : 64;

    // A = W1 rows j=g*16+lj, k = toff + ks*32 + lg*8 + e (verified layout from r1/r2)
    short8 afrag[2][2];
#pragma unroll
    for (int ks = 0; ks < 2; ++ks)
#pragma unroll
        for (int g = 0; g < 2; ++g)
            afrag[ks][g] = pack8(W1 + (g * 16 + lj) * 128 + toff + ks * 32 + lg * 8);

    int r = tb + lj; if (r >= nrows) r = nrows - 1;
    const float* rp = tab + (long)r * 64;
    short8 bfrag0 = pack8(rp + lg * 8);
    short8 bfrag1 = pack8(rp + 32 + lg * 8);

    f32x4 acc[2];
#pragma unroll
    for (int g = 0; g < 2; ++g)
#pragma unroll
        for (int q = 0; q < 4; ++q)
            acc[g][q] = isU ? b1[g * 16 + lg * 4 + q] : 0.f;   // fold b1 into user table only

    acc[0] = __builtin_amdgcn_mfma_f32_16x16x32_bf16(afrag[0][0], bfrag0, acc[0], 0, 0, 0);
    acc[1] = __builtin_amdgcn_mfma_f32_16x16x32_bf16(afrag[0][1], bfrag0, acc[1], 0, 0, 0);
    acc[0] = __builtin_amdgcn_mfma_f32_16x16x32_bf16(afrag[1][0], bfrag1, acc[0], 0, 0, 0);
    acc[1] = __builtin_amdgcn_mfma_f32_16x16x32_bf16(afrag[1][1], bfrag1, acc[1], 0, 0, 0);

    if (tb + lj < nrows) {
        // lane holds h[row=r][j = g*16 + lg*4 + q]
#pragma unroll
        for (int g = 0; g < 2; ++g) {
            h4v v;
#pragma unroll
            for (int q = 0; q < 4; ++q) v[q] = (_Float16)acc[g][q];
            *reinterpret_cast<h4v*>(ht + (long)r * 32 + g * 16 + lg * 4) = v;
        }
    }
}

#if __has_builtin(__builtin_amdgcn_fdot2)
__device__ __forceinline__ float fdot2(h2v a, h2v b, float c) {
    return __builtin_amdgcn_fdot2(a, b, c, false);
}
#else
__device__ __forceinline__ float fdot2(h2v a, h2v b, float c) {
    return c + (float)a[0] * (float)b[0] + (float)a[1] * (float)b[1];
}
#endif

// ---- main: 64 edges per wave (one shot). 4 lanes cooperate on one edge:
// each lane loads one 16-B quarter of the 64-B h-row (cache-line coalesced).
__global__ __launch_bounds__(256) void edge_final(
    const _Float16* __restrict__ hu, const _Float16* __restrict__ hi,
    const float* __restrict__ w2, const float* __restrict__ b2v,
    const int* __restrict__ idx, float* __restrict__ out,
    long E, long ngroups)
{
    const int l = threadIdx.x & 63;
    const int c = l & 3;    // chunk: h elements c*8 .. c*8+7
    const int g = l >> 2;   // edge-within-16

    long wid = (long)blockIdx.x * (blockDim.x >> 6) + (threadIdx.x >> 6);
    if (wid >= ngroups) return;

    h2v w2h[4];
#pragma unroll
    for (int k = 0; k < 4; ++k) {
        w2h[k][0] = (_Float16)w2[c * 8 + 2 * k];
        w2h[k][1] = (_Float16)w2[c * 8 + 2 * k + 1];
    }
    const float bb2 = b2v[0];
    const _Float16 sl = (_Float16)0.2f;
    const h2v slope = {sl, sl};

    long e0 = wid * 64;
    long el = e0 + l; if (el >= E) el = E - 1;
    int uidx = idx[el];        // coalesced: lane l <-> edge e0+l
    int iidx = idx[E + el];

    uint4 hur[4], hir[4];
#pragma unroll
    for (int s = 0; s < 4; ++s) {
        int u  = __shfl(uidx, s * 16 + g);
        int it = __shfl(iidx, s * 16 + g);
        hur[s] = *reinterpret_cast<const uint4*>(hu + (long)u  * 32 + c * 8);
        hir[s] = *reinterpret_cast<const uint4*>(hi + (long)it * 32 + c * 8);
    }

    float pt[4];
#pragma unroll
    for (int s = 0; s < 4; ++s) {
        const unsigned int* au = reinterpret_cast<const unsigned int*>(&hur[s]);
        const unsigned int* ai = reinterpret_cast<const unsigned int*>(&hir[s]);
        float p = 0.f;
#pragma unroll
        for (int k = 0; k < 4; ++k) {
            h2v a = __builtin_bit_cast(h2v, au[k]);
            h2v b = __builtin_bit_cast(h2v, ai[k]);
            h2v h = a + b;
            h = __builtin_elementwise_max(h, h * slope);   // LeakyReLU(0.2)
            p = fdot2(h, w2h[k], p);
        }
        p += __shfl_xor(p, 1);   // reduce over the 4 chunk-lanes
        p += __shfl_xor(p, 2);
        pt[s] = p;
    }

    // lane l wants edge e0+l = subround l>>4, position l&15 (logit at lane (l&15)*4)
    int src = (l & 15) * 4;
    float v0 = __shfl(pt[0], src);
    float v1 = __shfl(pt[1], src);
    float v2 = __shfl(pt[2], src);
    float v3 = __shfl(pt[3], src);
    int sr = l >> 4;
    float pv = sr == 0 ? v0 : sr == 1 ? v1 : sr == 2 ? v2 : v3;

    float x = pv + bb2;
    float z = __builtin_amdgcn_exp2f(-1.442695040888963f * x);
    float sig = __builtin_amdgcn_rcpf(1.f + z);
    long eo = e0 + l;
    if (eo < E) out[eo] = sig;   // coalesced 256-B store
}

// ---- fallback (ws too small): fp32 VALU, thread-per-edge, W1 in LDS ----
__global__ __launch_bounds__(256) void edge_mlp_fp32(
    const float* __restrict__ ue, const float* __restrict__ ie,
    const float* __restrict__ W1, const float* __restrict__ b1,
    const float* __restrict__ w2, const float* __restrict__ b2v,
    const int* __restrict__ idx, float* __restrict__ out, long E)
{
    __shared__ float w1s[128][32];
    for (int t = threadIdx.x; t < 4096; t += blockDim.x) {
        int k = t >> 5, j = t & 31;
        w1s[k][j] = W1[j * 128 + k];
    }
    __syncthreads();
    long e = (long)blockIdx.x * blockDim.x + threadIdx.x;
    if (e >= E) return;
    int u = idx[e], it = idx[E + e];
    const float* ur = ue + (long)u * 64;
    const float* ir = ie + (long)it * 64;
    float acc[32];
#pragma unroll
    for (int j = 0; j < 32; ++j) acc[j] = b1[j];
    for (int k = 0; k < 64; k += 4) {
        float4 f = *reinterpret_cast<const float4*>(ur + k);
        float fv[4] = {f.x, f.y, f.z, f.w};
#pragma unroll
        for (int q = 0; q < 4; ++q)
#pragma unroll
            for (int j = 0; j < 32; ++j) acc[j] += w1s[k + q][j] * fv[q];
    }
    for (int k = 0; k < 64; k += 4) {
        float4 f = *reinterpret_cast<const float4*>(ir + k);
        float fv[4] = {f.x, f.y, f.z, f.w};
#pragma unroll
        for (int q = 0; q < 4; ++q)
#pragma unroll
            for (int j = 0; j < 32; ++j) acc[j] += w1s[64 + k + q][j] * fv[q];
    }
    float lgt = b2v[0];
#pragma unroll
    for (int j = 0; j < 32; ++j) {
        float h = acc[j]; h = h >= 0.f ? h : 0.2f * h;
        lgt += h * w2[j];
    }
    out[e] = 1.0f / (1.0f + expf(-lgt));
}

extern "C" void kernel_launch(void* const* d_in, const int* in_sizes, int n_in,
                              void* d_out, int out_size, void* d_ws, size_t ws_size,
                              hipStream_t stream) {
    const float* ue  = (const float*)d_in[0];
    const float* ie  = (const float*)d_in[1];
    const float* W1  = (const float*)d_in[2];
    const float* b1  = (const float*)d_in[3];
    const float* w2  = (const float*)d_in[4];
    const float* b2v = (const float*)d_in[5];
    const int*   idx = (const int*)d_in[6];
    float* out = (float*)d_out;

    long nu = in_sizes[0] / 64;
    long ni = in_sizes[1] / 64;
    long E  = in_sizes[6] / 2;

    size_t need = (size_t)(nu + ni) * 32 * sizeof(_Float16);
    if (ws_size >= need) {
        _Float16* hu = (_Float16*)d_ws;
        _Float16* hi = hu + (size_t)nu * 32;

        int ntu = (int)((nu + 15) / 16);
        int nti = (int)((ni + 15) / 16);
        int ntot = ntu + nti;
        int pblocks = (ntot + 3) / 4;   // 4 waves per 256-thread block
        precompute_h<<<pblocks, 256, 0, stream>>>(ue, ie, W1, b1, hu, hi,
                                                  (int)nu, (int)ni, ntu, ntot);

        long ngroups = (E + 63) / 64;
        int mblocks = (int)((ngroups + 3) / 4);
        edge_final<<<mblocks, 256, 0, stream>>>(hu, hi, w2, b2v, idx, out, E, ngroups);
    } else {
        edge_mlp_fp32<<<(int)((E + 255) / 256), 256, 0, stream>>>(
            ue, ie, W1, b1, w2, b2v, idx, out, E);
    }
}